// Round 8
// baseline (1036.126 us; speedup 1.0000x reference)
//
#include <hip/hip_runtime.h>
#include <hip/hip_bf16.h>

// SpikingPolicyNet: B=8192, D_in=256, H=1024, D_out=64, T=15, TAU=20, V_TH=1
//
// Pipeline:
//  K0 : W2 -> W2cb (bf16 W2^T) + W2p (relu'd bf16 W2^T + zero pad row);
//       zeroes the rare-row counter (ws is not re-poisoned between replays).
//  K1 : bf16-MFMA x@W1.T; epilogue folds b1 and emits the closed-form spike
//       interval k = ceil(log2(1-1/I)/log2(0.95)) as a byte plane kb[b][j]
//       (layer-1 spikes at t = k,2k,...; I1 is time-invariant).
//  K2 : block-per-row FAST PATH ONLY. Flat spiker list (one LDS atomic
//       counter), then U = b2 + sum_spikers relu(W2 col) >= max_t I2_t,
//       8 independent loads per chunk (explicit scalars, no launch-bounds
//       squeeze). Induction v2_t <= U*(1-.95^t) < U, so U <= 0.999 (1e-3
//       margin >> fp drift) proves zero s2 spikes. Rows failing the bound
//       are appended to a global list; out = bout written unconditionally.
//  K3 : rare exact path, grid-stride over the flagged-row list (empirically
//       empty: absmax==0 in R1-R7 incl. full-fp32 R1); overwrites out[row].

#define B_SZ   8192
#define D_IN   256
#define H_SZ   1024
#define D_OUT  64
#define T_STEPS 15
#define SKIP_THR 0.999f

typedef __attribute__((ext_vector_type(8))) short short8;
typedef __attribute__((ext_vector_type(4))) float f32x4;

static __device__ __forceinline__ unsigned int pk_bf16(float lo, float hi) {
    return (__builtin_bit_cast(unsigned int, hi) & 0xffff0000u) |
           (__builtin_bit_cast(unsigned int, lo) >> 16);
}
static __device__ __forceinline__ float bf_lo(unsigned int u) {
    return __builtin_bit_cast(float, u << 16);
}
static __device__ __forceinline__ float bf_hi(unsigned int u) {
    return __builtin_bit_cast(float, u & 0xffff0000u);
}

// ---------------------------------------------------------------- K0: W2 -> W2cb + W2p(+pad), zero gcnt
__global__ __launch_bounds__(256) void k0_transpose(const float* __restrict__ W2,
                                                    unsigned short* __restrict__ W2cb,
                                                    unsigned short* __restrict__ W2p,
                                                    int* __restrict__ gcnt) {
    __shared__ float tile[32][33];
    const int bx = blockIdx.x * 32;
    const int by = blockIdx.y * 32;
    const int tx = threadIdx.x;
    const int ty = threadIdx.y;
    #pragma unroll
    for (int i = ty; i < 32; i += 8)
        tile[i][tx] = W2[(by + i) * H_SZ + bx + tx];
    __syncthreads();
    #pragma unroll
    for (int i = ty; i < 32; i += 8) {
        const unsigned int uv = __builtin_bit_cast(unsigned int, tile[tx][i]);
        const unsigned short bf = (unsigned short)(uv >> 16);
        const size_t idx = (size_t)(bx + i) * H_SZ + by + tx;
        W2cb[idx] = bf;
        W2p[idx]  = (bf & 0x8000u) ? (unsigned short)0 : bf;   // relu (exact on bf16)
    }
    if (blockIdx.x == 0 && blockIdx.y == 0) {
        const int t = ty * 32 + tx;
        #pragma unroll
        for (int i = 0; i < 4; ++i)                             // zero pad row 1024
            W2p[(size_t)H_SZ * H_SZ + i * 256 + t] = 0;
        if (t == 0) *gcnt = 0;                                  // reset rare counter
    }
}

// ---------------------------------------------------------------- K1: interval byte-plane from x@W1.T+b1
__global__ __launch_bounds__(256) void k1_mfma(const float* __restrict__ A,
                                               const float* __restrict__ Bw,
                                               const float* __restrict__ b1,
                                               unsigned char* __restrict__ kb) {
    __shared__ unsigned int As4[2048];   // 128 rows x 32 bf16, 16B-chunk XOR swizzle
    __shared__ unsigned int Bs4[2048];
    const int tid  = threadIdx.x;
    const int m0   = blockIdx.x * 128;
    const int n0   = blockIdx.y * 128;
    const int lane = tid & 63;
    const int wid  = tid >> 6;
    const int wr   = wid >> 1, wc = wid & 1;

    const int row0 = tid >> 2;
    const int row1 = row0 + 64;
    const int q0   = tid & 3;

    f32x4 acc[4][4] = {};
    float4 s0[8], s1[8];

    auto LOAD = [&](float4* s, int kbk) {
        const float* pa0 = A  + (m0 + row0) * D_IN + kbk + q0 * 8;
        const float* pa1 = A  + (m0 + row1) * D_IN + kbk + q0 * 8;
        const float* pb0 = Bw + (n0 + row0) * D_IN + kbk + q0 * 8;
        const float* pb1 = Bw + (n0 + row1) * D_IN + kbk + q0 * 8;
        s[0] = *(const float4*)pa0; s[1] = *(const float4*)(pa0 + 4);
        s[2] = *(const float4*)pa1; s[3] = *(const float4*)(pa1 + 4);
        s[4] = *(const float4*)pb0; s[5] = *(const float4*)(pb0 + 4);
        s[6] = *(const float4*)pb1; s[7] = *(const float4*)(pb1 + 4);
    };
    auto WRITE = [&](const float4* s) {
        const int i0 = row0 * 16 + (q0 ^ ((row0 >> 1) & 3)) * 4;
        const int i1 = row1 * 16 + (q0 ^ ((row1 >> 1) & 3)) * 4;
        *(uint4*)&As4[i0] = make_uint4(pk_bf16(s[0].x, s[0].y), pk_bf16(s[0].z, s[0].w),
                                       pk_bf16(s[1].x, s[1].y), pk_bf16(s[1].z, s[1].w));
        *(uint4*)&As4[i1] = make_uint4(pk_bf16(s[2].x, s[2].y), pk_bf16(s[2].z, s[2].w),
                                       pk_bf16(s[3].x, s[3].y), pk_bf16(s[3].z, s[3].w));
        *(uint4*)&Bs4[i0] = make_uint4(pk_bf16(s[4].x, s[4].y), pk_bf16(s[4].z, s[4].w),
                                       pk_bf16(s[5].x, s[5].y), pk_bf16(s[5].z, s[5].w));
        *(uint4*)&Bs4[i1] = make_uint4(pk_bf16(s[6].x, s[6].y), pk_bf16(s[6].z, s[6].w),
                                       pk_bf16(s[7].x, s[7].y), pk_bf16(s[7].z, s[7].w));
    };
    auto COMPUTE = [&]() {
        short8 afr[4], bfr[4];
        const int q  = lane >> 4;
        const int lr = lane & 15;
        #pragma unroll
        for (int mf = 0; mf < 4; ++mf) {
            const int ra = wr * 64 + mf * 16 + lr;
            afr[mf] = *(const short8*)&As4[ra * 16 + (q ^ ((ra >> 1) & 3)) * 4];
            const int rb = wc * 64 + mf * 16 + lr;
            bfr[mf] = *(const short8*)&Bs4[rb * 16 + (q ^ ((rb >> 1) & 3)) * 4];
        }
        #pragma unroll
        for (int mf = 0; mf < 4; ++mf)
            #pragma unroll
            for (int nf = 0; nf < 4; ++nf)
                acc[mf][nf] = __builtin_amdgcn_mfma_f32_16x16x32_bf16(
                    afr[mf], bfr[nf], acc[mf][nf], 0, 0, 0);
    };

    LOAD(s0, 0);
    for (int kk = 0; kk < D_IN; kk += 64) {
        if (kk + 32 < D_IN) LOAD(s1, kk + 32);
        __syncthreads();
        WRITE(s0);
        __syncthreads();
        COMPUTE();
        if (kk + 64 < D_IN) LOAD(s0, kk + 64);
        __syncthreads();
        WRITE(s1);
        __syncthreads();
        COMPUTE();
    }

    // Epilogue: I = acc + b1[col]; k = ceil(log2(1-1/I)*-13.5134035), 0 = none.
    // C/D layout (m89): col = lane&15, row = (lane>>4)*4 + r. Byte-plane store.
    const int lr = lane & 15;
    const int qq = lane >> 4;
    float b1v[4];
    #pragma unroll
    for (int nf = 0; nf < 4; ++nf) b1v[nf] = b1[n0 + wc * 64 + nf * 16 + lr];

    #pragma unroll
    for (int mf = 0; mf < 4; ++mf) {
        const int rbase = m0 + wr * 64 + mf * 16 + qq * 4;
        #pragma unroll
        for (int nf = 0; nf < 4; ++nf) {
            const int c = n0 + wc * 64 + nf * 16 + lr;
            #pragma unroll
            for (int r = 0; r < 4; ++r) {
                const float I = acc[mf][nf][r] + b1v[nf];
                int k = 0;
                if (I > 1.8632055f) {
                    const float l2 = __builtin_amdgcn_logf(1.0f - __builtin_amdgcn_rcpf(I));
                    int kc = (int)__builtin_ceilf(l2 * -13.5134035f);
                    k = kc < 1 ? 1 : (kc > 15 ? 15 : kc);
                }
                kb[(size_t)(rbase + r) * H_SZ + c] = (unsigned char)k;
            }
        }
    }
}

// ---------------------------------------------------------------- K2: fast bound pass (block-per-row)
__global__ __launch_bounds__(256) void k2_bound(const unsigned char* __restrict__ kb,
                                                const unsigned short* __restrict__ W2p,
                                                const float* __restrict__ b2,
                                                const float* __restrict__ bout,
                                                int* __restrict__ gcnt,
                                                int* __restrict__ glist,
                                                float* __restrict__ out) {
    const int b   = blockIdx.x;
    const int tid = threadIdx.x;
    const int jc  = tid * 4;

    __shared__ unsigned int list[264];
    __shared__ int cnt;
    __shared__ int bflag;

    if (tid == 0) { cnt = 0; bflag = 0; }

    const unsigned int kw = *(const unsigned int*)(kb + (size_t)b * H_SZ + jc);
    const float4 b2v = *(const float4*)&b2[jc];
    __syncthreads();

    if (kw) {
        #pragma unroll
        for (int u = 0; u < 4; ++u)
            if ((kw >> (8 * u)) & 0xffu) {
                const int p = atomicAdd(&cnt, 1);
                list[p] = (unsigned int)(jc + u);
            }
    }
    __syncthreads();
    const int n = cnt;

    float U0 = b2v.x, U1 = b2v.y, U2 = b2v.z, U3 = b2v.w;
    for (int s = 0; s < n; s += 8) {
        const uint4 ea = *(const uint4*)&list[s];        // broadcast LDS reads
        const uint4 eb = *(const uint4*)&list[s + 4];
        const int j0 = (int)ea.x;                         // s+0 < n guaranteed
        const int j1 = (s + 1 < n) ? (int)ea.y : H_SZ;    // pad row -> zeros
        const int j2 = (s + 2 < n) ? (int)ea.z : H_SZ;
        const int j3 = (s + 3 < n) ? (int)ea.w : H_SZ;
        const int j4 = (s + 4 < n) ? (int)eb.x : H_SZ;
        const int j5 = (s + 5 < n) ? (int)eb.y : H_SZ;
        const int j6 = (s + 6 < n) ? (int)eb.z : H_SZ;
        const int j7 = (s + 7 < n) ? (int)eb.w : H_SZ;
        const uint2 w0 = *(const uint2*)(W2p + ((size_t)j0 << 10) + jc);
        const uint2 w1 = *(const uint2*)(W2p + ((size_t)j1 << 10) + jc);
        const uint2 w2 = *(const uint2*)(W2p + ((size_t)j2 << 10) + jc);
        const uint2 w3 = *(const uint2*)(W2p + ((size_t)j3 << 10) + jc);
        const uint2 w4 = *(const uint2*)(W2p + ((size_t)j4 << 10) + jc);
        const uint2 w5 = *(const uint2*)(W2p + ((size_t)j5 << 10) + jc);
        const uint2 w6 = *(const uint2*)(W2p + ((size_t)j6 << 10) + jc);
        const uint2 w7 = *(const uint2*)(W2p + ((size_t)j7 << 10) + jc);
        U0 += bf_lo(w0.x); U1 += bf_hi(w0.x); U2 += bf_lo(w0.y); U3 += bf_hi(w0.y);
        U0 += bf_lo(w1.x); U1 += bf_hi(w1.x); U2 += bf_lo(w1.y); U3 += bf_hi(w1.y);
        U0 += bf_lo(w2.x); U1 += bf_hi(w2.x); U2 += bf_lo(w2.y); U3 += bf_hi(w2.y);
        U0 += bf_lo(w3.x); U1 += bf_hi(w3.x); U2 += bf_lo(w3.y); U3 += bf_hi(w3.y);
        U0 += bf_lo(w4.x); U1 += bf_hi(w4.x); U2 += bf_lo(w4.y); U3 += bf_hi(w4.y);
        U0 += bf_lo(w5.x); U1 += bf_hi(w5.x); U2 += bf_lo(w5.y); U3 += bf_hi(w5.y);
        U0 += bf_lo(w6.x); U1 += bf_hi(w6.x); U2 += bf_lo(w6.y); U3 += bf_hi(w6.y);
        U0 += bf_lo(w7.x); U1 += bf_hi(w7.x); U2 += bf_lo(w7.y); U3 += bf_hi(w7.y);
    }

    const bool need = (U0 > SKIP_THR) || (U1 > SKIP_THR) ||
                      (U2 > SKIP_THR) || (U3 > SKIP_THR);
    if (need) atomicOr(&bflag, 1);        // ~never executes
    __syncthreads();
    if (tid == 0 && bflag) { const int x = atomicAdd(gcnt, 1); glist[x] = b; }

    if (tid < D_OUT) out[(size_t)b * D_OUT + tid] = bout[tid];
}

// ---------------------------------------------------------------- K3: rare exact path (grid-stride)
__global__ __launch_bounds__(256) void k3_rare(const unsigned char* __restrict__ kb,
                                               const unsigned short* __restrict__ W2cb,
                                               const float* __restrict__ b2,
                                               const float* __restrict__ Wout,
                                               const float* __restrict__ bout,
                                               const int* __restrict__ gcnt,
                                               const int* __restrict__ glist,
                                               float* __restrict__ out) {
    __shared__ unsigned int list[264];
    __shared__ int cnt;
    __shared__ float rrow[H_SZ];
    const int tid = threadIdx.x;
    const int jc  = tid * 4;
    const int total = *gcnt;                      // uniform

    for (int idx = blockIdx.x; idx < total; idx += gridDim.x) {
        const int b = glist[idx];
        if (tid == 0) cnt = 0;
        __syncthreads();

        const unsigned int kw = *(const unsigned int*)(kb + (size_t)b * H_SZ + jc);
        const float4 b2v = *(const float4*)&b2[jc];
        #pragma unroll
        for (int u = 0; u < 4; ++u) {
            const unsigned int ku = (kw >> (8 * u)) & 0xffu;
            if (ku) {
                const int p = atomicAdd(&cnt, 1);
                list[p] = ((unsigned int)(jc + u) << 8) | ku;
            }
        }
        __syncthreads();
        const int n = cnt;

        float v0 = 0.f, v1 = 0.f, v2 = 0.f, v3 = 0.f;
        int c0 = 0, c1 = 0, c2 = 0, c3 = 0;
        for (int t = 1; t <= T_STEPS; ++t) {
            float i0 = b2v.x, i1 = b2v.y, i2 = b2v.z, i3 = b2v.w;
            for (int s = 0; s < n; ++s) {
                const unsigned int e = list[s];
                const int k = (int)(e & 255u);
                if ((t % k) == 0) {
                    const int j = (int)(e >> 8);
                    const uint2 w = *(const uint2*)(W2cb + ((size_t)j << 10) + jc);
                    i0 += bf_lo(w.x); i1 += bf_hi(w.x);
                    i2 += bf_lo(w.y); i3 += bf_hi(w.y);
                }
            }
            v0 = fmaf(i0, 0.05f, v0 * 0.95f); if (v0 > 1.0f) { v0 = 0.f; ++c0; }
            v1 = fmaf(i1, 0.05f, v1 * 0.95f); if (v1 > 1.0f) { v1 = 0.f; ++c1; }
            v2 = fmaf(i2, 0.05f, v2 * 0.95f); if (v2 > 1.0f) { v2 = 0.f; ++c2; }
            v3 = fmaf(i3, 0.05f, v3 * 0.95f); if (v3 > 1.0f) { v3 = 0.f; ++c3; }
        }

        rrow[jc + 0] = (float)c0 / 15.0f;
        rrow[jc + 1] = (float)c1 / 15.0f;
        rrow[jc + 2] = (float)c2 / 15.0f;
        rrow[jc + 3] = (float)c3 / 15.0f;
        __syncthreads();
        if (tid < D_OUT) {
            float a = bout[tid];
            const float* wr = Wout + (size_t)tid * H_SZ;
            for (int j = 0; j < H_SZ; ++j) a = fmaf(rrow[j], wr[j], a);
            out[(size_t)b * D_OUT + tid] = a;
        }
        __syncthreads();                  // before list/cnt/rrow reuse
    }
}

// ---------------------------------------------------------------- launch
extern "C" void kernel_launch(void* const* d_in, const int* in_sizes, int n_in,
                              void* d_out, int out_size, void* d_ws, size_t ws_size,
                              hipStream_t stream) {
    const float* x    = (const float*)d_in[0];
    const float* W1   = (const float*)d_in[1];
    const float* b1   = (const float*)d_in[2];
    const float* W2   = (const float*)d_in[3];
    const float* b2   = (const float*)d_in[4];
    const float* Wout = (const float*)d_in[5];
    const float* bout = (const float*)d_in[6];
    float* out = (float*)d_out;

    char* ws = (char*)d_ws;
    unsigned short* W2cb = (unsigned short*)(ws);                 // 2 MB (signed)
    unsigned short* W2p  = (unsigned short*)(ws + (2 << 20));     // 2 MB + 2 KB pad row
    int*            gcnt = (int*)(ws + (6 << 20));                // 4 B
    int*            glist = (int*)(ws + (6 << 20) + 4096);        // 32 KB
    unsigned char*  kbuf = (unsigned char*)(ws + (8 << 20));      // 8 MB intervals

    k0_transpose<<<dim3(H_SZ / 32, H_SZ / 32), dim3(32, 8), 0, stream>>>(W2, W2cb, W2p, gcnt);
    k1_mfma<<<dim3(B_SZ / 128, H_SZ / 128), 256, 0, stream>>>(x, W1, b1, kbuf);
    k2_bound<<<B_SZ, 256, 0, stream>>>(kbuf, W2p, b2, bout, gcnt, glist, out);
    k3_rare<<<64, 256, 0, stream>>>(kbuf, W2cb, b2, Wout, bout, gcnt, glist, out);
}

// Round 9
// 161.981 us; speedup vs baseline: 6.3966x; 6.3966x over previous
//
#include <hip/hip_runtime.h>
#include <hip/hip_bf16.h>

// SpikingPolicyNet: B=8192, D_in=256, H=1024, D_out=64, T=15, TAU=20, V_TH=1
//
// Pipeline:
//  K0 : W2 -> W2cb (bf16 W2^T, row 1024 = zero pad for masked tail loads)
//  K1 : bf16-MFMA x@W1.T; epilogue folds b1 and emits the closed-form spike
//       interval k = ceil(log2(1-1/I)/log2(0.95)) as byte plane kb[b][j]
//       (layer-1 spikes at t = k,2k,...; I1 is time-invariant).
//  K2 : block-per-row, EXACT. Flat spiker list (LDS atomic), 8-deep gather
//       accumulating signed bucket sums G_k (switch on wave-uniform k ->
//       static register indices). Tier A (no k<=7 spikers, ~92% of rows):
//       max_t I2_t == b2 + max(0, G_8..G_15) EXACTLY (t<=7 -> I2=b2; t>=8 ->
//       only divisor >=8 of t is t); <=0.999 proves no s2 spike (induction
//       v2_t <= max(0,M)(1-.95^t)). Tier B: exact 15-step recurrence from
//       the G registers via the divisor table. Rows with s2 spikes (never,
//       empirically; absmax==0 R1-R8 incl. full-fp32 R1) do an inline GEMV.

#define B_SZ   8192
#define D_IN   256
#define H_SZ   1024
#define D_OUT  64
#define T_STEPS 15
#define SKIP_THR 0.999f

typedef __attribute__((ext_vector_type(8))) short short8;
typedef __attribute__((ext_vector_type(4))) float f32x4;

static __device__ __forceinline__ unsigned int pk_bf16(float lo, float hi) {
    return (__builtin_bit_cast(unsigned int, hi) & 0xffff0000u) |
           (__builtin_bit_cast(unsigned int, lo) >> 16);
}
static __device__ __forceinline__ float bf_lo(unsigned int u) {
    return __builtin_bit_cast(float, u << 16);
}
static __device__ __forceinline__ float bf_hi(unsigned int u) {
    return __builtin_bit_cast(float, u & 0xffff0000u);
}
static __device__ __forceinline__ f32x4 unp4(uint2 w) {
    f32x4 r;
    r.x = bf_lo(w.x); r.y = bf_hi(w.x);
    r.z = bf_lo(w.y); r.w = bf_hi(w.y);
    return r;
}
static __device__ __forceinline__ f32x4 vmax4(f32x4 a, f32x4 b) {
    f32x4 r;
    r.x = fmaxf(a.x, b.x); r.y = fmaxf(a.y, b.y);
    r.z = fmaxf(a.z, b.z); r.w = fmaxf(a.w, b.w);
    return r;
}

// ---------------------------------------------------------------- K0: W2 -> W2cb (+zero pad row)
__global__ __launch_bounds__(256) void k0_transpose(const float* __restrict__ W2,
                                                    unsigned short* __restrict__ W2cb) {
    __shared__ float tile[32][33];
    const int bx = blockIdx.x * 32;
    const int by = blockIdx.y * 32;
    const int tx = threadIdx.x;
    const int ty = threadIdx.y;
    #pragma unroll
    for (int i = ty; i < 32; i += 8)
        tile[i][tx] = W2[(by + i) * H_SZ + bx + tx];
    __syncthreads();
    #pragma unroll
    for (int i = ty; i < 32; i += 8)
        W2cb[(size_t)(bx + i) * H_SZ + by + tx] =
            (unsigned short)(__builtin_bit_cast(unsigned int, tile[tx][i]) >> 16);
    if (blockIdx.x == 0 && blockIdx.y == 0) {                   // zero pad row 1024
        const int t = ty * 32 + tx;
        #pragma unroll
        for (int i = 0; i < 4; ++i)
            W2cb[(size_t)H_SZ * H_SZ + i * 256 + t] = 0;
    }
}

// ---------------------------------------------------------------- K1: interval byte-plane from x@W1.T+b1
__global__ __launch_bounds__(256) void k1_mfma(const float* __restrict__ A,
                                               const float* __restrict__ Bw,
                                               const float* __restrict__ b1,
                                               unsigned char* __restrict__ kb) {
    __shared__ unsigned int As4[2048];   // 128 rows x 32 bf16, 16B-chunk XOR swizzle
    __shared__ unsigned int Bs4[2048];
    const int tid  = threadIdx.x;
    const int m0   = blockIdx.x * 128;
    const int n0   = blockIdx.y * 128;
    const int lane = tid & 63;
    const int wid  = tid >> 6;
    const int wr   = wid >> 1, wc = wid & 1;

    const int row0 = tid >> 2;
    const int row1 = row0 + 64;
    const int q0   = tid & 3;

    f32x4 acc[4][4] = {};
    float4 s0[8], s1[8];

    auto LOAD = [&](float4* s, int kbk) {
        const float* pa0 = A  + (m0 + row0) * D_IN + kbk + q0 * 8;
        const float* pa1 = A  + (m0 + row1) * D_IN + kbk + q0 * 8;
        const float* pb0 = Bw + (n0 + row0) * D_IN + kbk + q0 * 8;
        const float* pb1 = Bw + (n0 + row1) * D_IN + kbk + q0 * 8;
        s[0] = *(const float4*)pa0; s[1] = *(const float4*)(pa0 + 4);
        s[2] = *(const float4*)pa1; s[3] = *(const float4*)(pa1 + 4);
        s[4] = *(const float4*)pb0; s[5] = *(const float4*)(pb0 + 4);
        s[6] = *(const float4*)pb1; s[7] = *(const float4*)(pb1 + 4);
    };
    auto WRITE = [&](const float4* s) {
        const int i0 = row0 * 16 + (q0 ^ ((row0 >> 1) & 3)) * 4;
        const int i1 = row1 * 16 + (q0 ^ ((row1 >> 1) & 3)) * 4;
        *(uint4*)&As4[i0] = make_uint4(pk_bf16(s[0].x, s[0].y), pk_bf16(s[0].z, s[0].w),
                                       pk_bf16(s[1].x, s[1].y), pk_bf16(s[1].z, s[1].w));
        *(uint4*)&As4[i1] = make_uint4(pk_bf16(s[2].x, s[2].y), pk_bf16(s[2].z, s[2].w),
                                       pk_bf16(s[3].x, s[3].y), pk_bf16(s[3].z, s[3].w));
        *(uint4*)&Bs4[i0] = make_uint4(pk_bf16(s[4].x, s[4].y), pk_bf16(s[4].z, s[4].w),
                                       pk_bf16(s[5].x, s[5].y), pk_bf16(s[5].z, s[5].w));
        *(uint4*)&Bs4[i1] = make_uint4(pk_bf16(s[6].x, s[6].y), pk_bf16(s[6].z, s[6].w),
                                       pk_bf16(s[7].x, s[7].y), pk_bf16(s[7].z, s[7].w));
    };
    auto COMPUTE = [&]() {
        short8 afr[4], bfr[4];
        const int q  = lane >> 4;
        const int lr = lane & 15;
        #pragma unroll
        for (int mf = 0; mf < 4; ++mf) {
            const int ra = wr * 64 + mf * 16 + lr;
            afr[mf] = *(const short8*)&As4[ra * 16 + (q ^ ((ra >> 1) & 3)) * 4];
            const int rb = wc * 64 + mf * 16 + lr;
            bfr[mf] = *(const short8*)&Bs4[rb * 16 + (q ^ ((rb >> 1) & 3)) * 4];
        }
        #pragma unroll
        for (int mf = 0; mf < 4; ++mf)
            #pragma unroll
            for (int nf = 0; nf < 4; ++nf)
                acc[mf][nf] = __builtin_amdgcn_mfma_f32_16x16x32_bf16(
                    afr[mf], bfr[nf], acc[mf][nf], 0, 0, 0);
    };

    LOAD(s0, 0);
    for (int kk = 0; kk < D_IN; kk += 64) {
        if (kk + 32 < D_IN) LOAD(s1, kk + 32);
        __syncthreads();
        WRITE(s0);
        __syncthreads();
        COMPUTE();
        if (kk + 64 < D_IN) LOAD(s0, kk + 64);
        __syncthreads();
        WRITE(s1);
        __syncthreads();
        COMPUTE();
    }

    // Epilogue: I = acc + b1[col]; k = ceil(log2(1-1/I)*-13.5134035), 0 = none.
    // C/D layout (m89): col = lane&15, row = (lane>>4)*4 + r. Byte-plane store.
    const int lr = lane & 15;
    const int qq = lane >> 4;
    float b1v[4];
    #pragma unroll
    for (int nf = 0; nf < 4; ++nf) b1v[nf] = b1[n0 + wc * 64 + nf * 16 + lr];

    #pragma unroll
    for (int mf = 0; mf < 4; ++mf) {
        const int rbase = m0 + wr * 64 + mf * 16 + qq * 4;
        #pragma unroll
        for (int nf = 0; nf < 4; ++nf) {
            const int c = n0 + wc * 64 + nf * 16 + lr;
            #pragma unroll
            for (int r = 0; r < 4; ++r) {
                const float I = acc[mf][nf][r] + b1v[nf];
                int k = 0;
                if (I > 1.8632055f) {
                    const float l2 = __builtin_amdgcn_logf(1.0f - __builtin_amdgcn_rcpf(I));
                    int kc = (int)__builtin_ceilf(l2 * -13.5134035f);
                    k = kc < 1 ? 1 : (kc > 15 ? 15 : kc);
                }
                kb[(size_t)(rbase + r) * H_SZ + c] = (unsigned char)k;
            }
        }
    }
}

// ---------------------------------------------------------------- K2: exact, block-per-row
#define PADE ((unsigned int)((H_SZ << 8) | 8))   // tail: zero row -> G8 += 0

#define APPLY(WW, KK)                                                         \
    switch (KK) {                                                             \
        case 1:  G1  += (WW); break;  case 2:  G2  += (WW); break;            \
        case 3:  G3  += (WW); break;  case 4:  G4  += (WW); break;            \
        case 5:  G5  += (WW); break;  case 6:  G6  += (WW); break;            \
        case 7:  G7  += (WW); break;  case 8:  G8  += (WW); break;            \
        case 9:  G9  += (WW); break;  case 10: G10 += (WW); break;            \
        case 11: G11 += (WW); break;  case 12: G12 += (WW); break;            \
        case 13: G13 += (WW); break;  case 14: G14 += (WW); break;            \
        case 15: G15 += (WW); break;  default: break;                         \
    }

#define STEP(I2EXPR)                                                          \
    { const f32x4 i2v = (I2EXPR);                                             \
      v2 = v2 * 0.95f + i2v * 0.05f;                                          \
      if (v2.x > 1.0f) { v2.x = 0.f; ++c0; }                                  \
      if (v2.y > 1.0f) { v2.y = 0.f; ++c1; }                                  \
      if (v2.z > 1.0f) { v2.z = 0.f; ++c2; }                                  \
      if (v2.w > 1.0f) { v2.w = 0.f; ++c3; } }

__global__ __launch_bounds__(256) void k2_snn(const unsigned char* __restrict__ kb,
                                              const unsigned short* __restrict__ W2cb,
                                              const float* __restrict__ b2,
                                              const float* __restrict__ Wout,
                                              const float* __restrict__ bout,
                                              float* __restrict__ out) {
    const int b   = blockIdx.x;
    const int tid = threadIdx.x;
    const int jc  = tid * 4;

    __shared__ unsigned int list[H_SZ];
    __shared__ int cnt;
    __shared__ int smallk;
    __shared__ int spikeflag;

    if (tid == 0) { cnt = 0; smallk = 0; spikeflag = 0; }

    const unsigned int kw = *(const unsigned int*)(kb + (size_t)b * H_SZ + jc);
    const f32x4 b2q = *(const f32x4*)&b2[jc];
    __syncthreads();

    if (kw) {
        #pragma unroll
        for (int u = 0; u < 4; ++u) {
            const unsigned int ku = (kw >> (8 * u)) & 0xffu;
            if (ku) {
                const int p = atomicAdd(&cnt, 1);
                list[p] = ((unsigned int)(jc + u) << 8) | ku;
                if (ku < 8) atomicOr(&smallk, 1);
            }
        }
    }
    __syncthreads();
    const int n = cnt;
    const bool hasSmall = (smallk != 0);

    f32x4 G1 = {0,0,0,0}, G2 = {0,0,0,0}, G3 = {0,0,0,0}, G4 = {0,0,0,0};
    f32x4 G5 = {0,0,0,0}, G6 = {0,0,0,0}, G7 = {0,0,0,0}, G8 = {0,0,0,0};
    f32x4 G9 = {0,0,0,0}, G10 = {0,0,0,0}, G11 = {0,0,0,0}, G12 = {0,0,0,0};
    f32x4 G13 = {0,0,0,0}, G14 = {0,0,0,0}, G15 = {0,0,0,0};

    for (int s = 0; s < n; s += 8) {
        const uint4 ea = *(const uint4*)&list[s];         // broadcast LDS reads
        const uint4 eb = *(const uint4*)&list[s + 4];
        const unsigned int e0 = ea.x;                     // s < n guaranteed
        const unsigned int e1 = (s + 1 < n) ? ea.y : PADE;
        const unsigned int e2 = (s + 2 < n) ? ea.z : PADE;
        const unsigned int e3 = (s + 3 < n) ? ea.w : PADE;
        const unsigned int e4 = (s + 4 < n) ? eb.x : PADE;
        const unsigned int e5 = (s + 5 < n) ? eb.y : PADE;
        const unsigned int e6 = (s + 6 < n) ? eb.z : PADE;
        const unsigned int e7 = (s + 7 < n) ? eb.w : PADE;
        const uint2 w0 = *(const uint2*)(W2cb + ((size_t)(e0 >> 8) << 10) + jc);
        const uint2 w1 = *(const uint2*)(W2cb + ((size_t)(e1 >> 8) << 10) + jc);
        const uint2 w2 = *(const uint2*)(W2cb + ((size_t)(e2 >> 8) << 10) + jc);
        const uint2 w3 = *(const uint2*)(W2cb + ((size_t)(e3 >> 8) << 10) + jc);
        const uint2 w4 = *(const uint2*)(W2cb + ((size_t)(e4 >> 8) << 10) + jc);
        const uint2 w5 = *(const uint2*)(W2cb + ((size_t)(e5 >> 8) << 10) + jc);
        const uint2 w6 = *(const uint2*)(W2cb + ((size_t)(e6 >> 8) << 10) + jc);
        const uint2 w7 = *(const uint2*)(W2cb + ((size_t)(e7 >> 8) << 10) + jc);
        { const f32x4 f = unp4(w0); const int kk = __builtin_amdgcn_readfirstlane((int)(e0 & 255u)); APPLY(f, kk) }
        { const f32x4 f = unp4(w1); const int kk = __builtin_amdgcn_readfirstlane((int)(e1 & 255u)); APPLY(f, kk) }
        { const f32x4 f = unp4(w2); const int kk = __builtin_amdgcn_readfirstlane((int)(e2 & 255u)); APPLY(f, kk) }
        { const f32x4 f = unp4(w3); const int kk = __builtin_amdgcn_readfirstlane((int)(e3 & 255u)); APPLY(f, kk) }
        { const f32x4 f = unp4(w4); const int kk = __builtin_amdgcn_readfirstlane((int)(e4 & 255u)); APPLY(f, kk) }
        { const f32x4 f = unp4(w5); const int kk = __builtin_amdgcn_readfirstlane((int)(e5 & 255u)); APPLY(f, kk) }
        { const f32x4 f = unp4(w6); const int kk = __builtin_amdgcn_readfirstlane((int)(e6 & 255u)); APPLY(f, kk) }
        { const f32x4 f = unp4(w7); const int kk = __builtin_amdgcn_readfirstlane((int)(e7 & 255u)); APPLY(f, kk) }
    }

    // ---- Tier A: no k<=7 spikers -> max_t I2_t == b2 + max(0, G8..G15) exactly
    bool slow = hasSmall;
    if (!hasSmall) {
        f32x4 gm = vmax4(G8, G9);
        gm = vmax4(gm, G10); gm = vmax4(gm, G11); gm = vmax4(gm, G12);
        gm = vmax4(gm, G13); gm = vmax4(gm, G14); gm = vmax4(gm, G15);
        const float M0 = b2q.x + fmaxf(gm.x, 0.f);
        const float M1 = b2q.y + fmaxf(gm.y, 0.f);
        const float M2 = b2q.z + fmaxf(gm.z, 0.f);
        const float M3 = b2q.w + fmaxf(gm.w, 0.f);
        slow = (M0 > SKIP_THR) || (M1 > SKIP_THR) ||
               (M2 > SKIP_THR) || (M3 > SKIP_THR);
    }

    // ---- Tier B: exact recurrence from G registers (divisor table)
    int c0 = 0, c1 = 0, c2 = 0, c3 = 0;
    if (slow) {
        f32x4 v2 = {0,0,0,0};
        const f32x4 D1 = b2q + G1;
        STEP(D1)                              // t=1
        STEP(D1 + G2)                         // t=2
        STEP(D1 + G3)                         // t=3
        STEP(D1 + G2 + G4)                    // t=4
        STEP(D1 + G5)                         // t=5
        STEP(D1 + G2 + G3 + G6)               // t=6
        STEP(D1 + G7)                         // t=7
        STEP(D1 + G2 + G4 + G8)               // t=8
        STEP(D1 + G3 + G9)                    // t=9
        STEP(D1 + G2 + G5 + G10)              // t=10
        STEP(D1 + G11)                        // t=11
        STEP(D1 + G2 + G3 + G4 + G6 + G12)    // t=12
        STEP(D1 + G13)                        // t=13
        STEP(D1 + G2 + G7 + G14)              // t=14
        STEP(D1 + G3 + G5 + G15)              // t=15
        if ((c0 | c1 | c2 | c3) != 0) atomicOr(&spikeflag, 1);
    }
    __syncthreads();

    if (spikeflag == 0) {                     // no s2 spikes: out = bout (bit-exact)
        if (tid < D_OUT) out[(size_t)b * D_OUT + tid] = bout[tid];
        return;
    }

    // ---- rare full readout (list is dead; reuse as rrow)
    float* rr = (float*)list;
    rr[jc + 0] = (float)c0 / 15.0f;
    rr[jc + 1] = (float)c1 / 15.0f;
    rr[jc + 2] = (float)c2 / 15.0f;
    rr[jc + 3] = (float)c3 / 15.0f;
    __syncthreads();
    if (tid < D_OUT) {
        float a = bout[tid];
        const float* wrow = Wout + (size_t)tid * H_SZ;
        for (int j = 0; j < H_SZ; ++j) a = fmaf(rr[j], wrow[j], a);
        out[(size_t)b * D_OUT + tid] = a;
    }
}

// ---------------------------------------------------------------- launch
extern "C" void kernel_launch(void* const* d_in, const int* in_sizes, int n_in,
                              void* d_out, int out_size, void* d_ws, size_t ws_size,
                              hipStream_t stream) {
    const float* x    = (const float*)d_in[0];
    const float* W1   = (const float*)d_in[1];
    const float* b1   = (const float*)d_in[2];
    const float* W2   = (const float*)d_in[3];
    const float* b2   = (const float*)d_in[4];
    const float* Wout = (const float*)d_in[5];
    const float* bout = (const float*)d_in[6];
    float* out = (float*)d_out;

    char* ws = (char*)d_ws;
    unsigned short* W2cb = (unsigned short*)(ws);              // 2 MB + 2 KB pad row
    unsigned char*  kbuf = (unsigned char*)(ws + (8 << 20));   // 8 MB intervals

    k0_transpose<<<dim3(H_SZ / 32, H_SZ / 32), dim3(32, 8), 0, stream>>>(W2, W2cb);
    k1_mfma<<<dim3(B_SZ / 128, H_SZ / 128), 256, 0, stream>>>(x, W1, b1, kbuf);
    k2_snn<<<B_SZ, 256, 0, stream>>>(kbuf, W2cb, b2, Wout, bout, out);
}

// Round 10
// 73.883 us; speedup vs baseline: 14.0238x; 2.1924x over previous
//
#include <hip/hip_runtime.h>
#include <hip/hip_bf16.h>

// SpikingPolicyNet: B=8192, D_in=256, H=1024, D_out=64, T=15, TAU=20, V_TH=1
//
// Pipeline:
//  K0 : W2 -> W2cb (bf16 W2^T, row 1024 zeroed = sentinel for padded entries)
//  K1 : bf16-MFMA x@W1.T; epilogue folds b1 and emits the closed-form spike
//       interval k = ceil(log2(1-1/I)/log2(0.95)) as byte plane kb[b][j]
//       (layer-1 spikes at t = k,2k,...; I1 time-invariant).
//  K2 : block-per-row. LDS bucket-sort by k (buckets padded to x4 with the
//       zero-row sentinel -> branchless quads). 15 STATICALLY-UNROLLED bucket
//       loops with scalar bounds: k=8..15 -> named G8..G15 (each t>=8 has
//       exactly one divisor >=8); k=1..7 -> one relu-sum Ps. No dynamic
//       register targeting anywhere (the R4/R9 spill/if-convert trap).
//       Certificate: M = b2 + Ps + relu(max G8..15) >= max_t I2_t; M<=0.999
//       (margin >> fp drift) + induction v2_t <= M(1-.95^t) < 1 proves zero
//       s2 spikes -> out = bout bit-exact (absmax==0 in R1-R9 incl fp32 R1).
//       Cert-failing rows (rare) run the exact per-step re-gather inline.

#define B_SZ   8192
#define D_IN   256
#define H_SZ   1024
#define D_OUT  64
#define T_STEPS 15
#define SKIP_THR 0.999f

typedef __attribute__((ext_vector_type(8))) short short8;
typedef __attribute__((ext_vector_type(4))) float f32x4;

static __device__ __forceinline__ unsigned int pk_bf16(float lo, float hi) {
    return (__builtin_bit_cast(unsigned int, hi) & 0xffff0000u) |
           (__builtin_bit_cast(unsigned int, lo) >> 16);
}
static __device__ __forceinline__ f32x4 unp4(uint2 w) {
    f32x4 r;
    r.x = __builtin_bit_cast(float, w.x << 16);
    r.y = __builtin_bit_cast(float, w.x & 0xffff0000u);
    r.z = __builtin_bit_cast(float, w.y << 16);
    r.w = __builtin_bit_cast(float, w.y & 0xffff0000u);
    return r;
}
static __device__ __forceinline__ f32x4 relu4(f32x4 a) {
    a.x = fmaxf(a.x, 0.f); a.y = fmaxf(a.y, 0.f);
    a.z = fmaxf(a.z, 0.f); a.w = fmaxf(a.w, 0.f);
    return a;
}
static __device__ __forceinline__ f32x4 vmax4(f32x4 a, f32x4 b) {
    f32x4 r;
    r.x = fmaxf(a.x, b.x); r.y = fmaxf(a.y, b.y);
    r.z = fmaxf(a.z, b.z); r.w = fmaxf(a.w, b.w);
    return r;
}

// ---------------------------------------------------------------- K0: W2 -> W2cb (+zero pad row)
__global__ __launch_bounds__(256) void k0_transpose(const float* __restrict__ W2,
                                                    unsigned short* __restrict__ W2cb) {
    __shared__ float tile[32][33];
    const int bx = blockIdx.x * 32;
    const int by = blockIdx.y * 32;
    const int tx = threadIdx.x;
    const int ty = threadIdx.y;
    #pragma unroll
    for (int i = ty; i < 32; i += 8)
        tile[i][tx] = W2[(by + i) * H_SZ + bx + tx];
    __syncthreads();
    #pragma unroll
    for (int i = ty; i < 32; i += 8)
        W2cb[(size_t)(bx + i) * H_SZ + by + tx] =
            (unsigned short)(__builtin_bit_cast(unsigned int, tile[tx][i]) >> 16);
    if (blockIdx.x == 0 && blockIdx.y == 0) {                   // zero sentinel row 1024
        const int t = ty * 32 + tx;
        #pragma unroll
        for (int i = 0; i < 4; ++i)
            W2cb[(size_t)H_SZ * H_SZ + i * 256 + t] = 0;
    }
}

// ---------------------------------------------------------------- K1: interval byte-plane from x@W1.T+b1
__global__ __launch_bounds__(256) void k1_mfma(const float* __restrict__ A,
                                               const float* __restrict__ Bw,
                                               const float* __restrict__ b1,
                                               unsigned char* __restrict__ kb) {
    __shared__ unsigned int As4[2048];   // 128 rows x 32 bf16, 16B-chunk XOR swizzle
    __shared__ unsigned int Bs4[2048];
    const int tid  = threadIdx.x;
    const int m0   = blockIdx.x * 128;
    const int n0   = blockIdx.y * 128;
    const int lane = tid & 63;
    const int wid  = tid >> 6;
    const int wr   = wid >> 1, wc = wid & 1;

    const int row0 = tid >> 2;
    const int row1 = row0 + 64;
    const int q0   = tid & 3;

    f32x4 acc[4][4] = {};
    float4 s0[8], s1[8];

    auto LOAD = [&](float4* s, int kbk) {
        const float* pa0 = A  + (m0 + row0) * D_IN + kbk + q0 * 8;
        const float* pa1 = A  + (m0 + row1) * D_IN + kbk + q0 * 8;
        const float* pb0 = Bw + (n0 + row0) * D_IN + kbk + q0 * 8;
        const float* pb1 = Bw + (n0 + row1) * D_IN + kbk + q0 * 8;
        s[0] = *(const float4*)pa0; s[1] = *(const float4*)(pa0 + 4);
        s[2] = *(const float4*)pa1; s[3] = *(const float4*)(pa1 + 4);
        s[4] = *(const float4*)pb0; s[5] = *(const float4*)(pb0 + 4);
        s[6] = *(const float4*)pb1; s[7] = *(const float4*)(pb1 + 4);
    };
    auto WRITE = [&](const float4* s) {
        const int i0 = row0 * 16 + (q0 ^ ((row0 >> 1) & 3)) * 4;
        const int i1 = row1 * 16 + (q0 ^ ((row1 >> 1) & 3)) * 4;
        *(uint4*)&As4[i0] = make_uint4(pk_bf16(s[0].x, s[0].y), pk_bf16(s[0].z, s[0].w),
                                       pk_bf16(s[1].x, s[1].y), pk_bf16(s[1].z, s[1].w));
        *(uint4*)&As4[i1] = make_uint4(pk_bf16(s[2].x, s[2].y), pk_bf16(s[2].z, s[2].w),
                                       pk_bf16(s[3].x, s[3].y), pk_bf16(s[3].z, s[3].w));
        *(uint4*)&Bs4[i0] = make_uint4(pk_bf16(s[4].x, s[4].y), pk_bf16(s[4].z, s[4].w),
                                       pk_bf16(s[5].x, s[5].y), pk_bf16(s[5].z, s[5].w));
        *(uint4*)&Bs4[i1] = make_uint4(pk_bf16(s[6].x, s[6].y), pk_bf16(s[6].z, s[6].w),
                                       pk_bf16(s[7].x, s[7].y), pk_bf16(s[7].z, s[7].w));
    };
    auto COMPUTE = [&]() {
        short8 afr[4], bfr[4];
        const int q  = lane >> 4;
        const int lr = lane & 15;
        #pragma unroll
        for (int mf = 0; mf < 4; ++mf) {
            const int ra = wr * 64 + mf * 16 + lr;
            afr[mf] = *(const short8*)&As4[ra * 16 + (q ^ ((ra >> 1) & 3)) * 4];
            const int rb = wc * 64 + mf * 16 + lr;
            bfr[mf] = *(const short8*)&Bs4[rb * 16 + (q ^ ((rb >> 1) & 3)) * 4];
        }
        #pragma unroll
        for (int mf = 0; mf < 4; ++mf)
            #pragma unroll
            for (int nf = 0; nf < 4; ++nf)
                acc[mf][nf] = __builtin_amdgcn_mfma_f32_16x16x32_bf16(
                    afr[mf], bfr[nf], acc[mf][nf], 0, 0, 0);
    };

    LOAD(s0, 0);
    for (int kk = 0; kk < D_IN; kk += 64) {
        if (kk + 32 < D_IN) LOAD(s1, kk + 32);
        __syncthreads();
        WRITE(s0);
        __syncthreads();
        COMPUTE();
        if (kk + 64 < D_IN) LOAD(s0, kk + 64);
        __syncthreads();
        WRITE(s1);
        __syncthreads();
        COMPUTE();
    }

    // Epilogue: I = acc + b1[col]; k = ceil(log2(1-1/I)*-13.5134035), 0 = none.
    const int lr = lane & 15;
    const int qq = lane >> 4;
    float b1v[4];
    #pragma unroll
    for (int nf = 0; nf < 4; ++nf) b1v[nf] = b1[n0 + wc * 64 + nf * 16 + lr];

    #pragma unroll
    for (int mf = 0; mf < 4; ++mf) {
        const int rbase = m0 + wr * 64 + mf * 16 + qq * 4;
        #pragma unroll
        for (int nf = 0; nf < 4; ++nf) {
            const int c = n0 + wc * 64 + nf * 16 + lr;
            #pragma unroll
            for (int r = 0; r < 4; ++r) {
                const float I = acc[mf][nf][r] + b1v[nf];
                int k = 0;
                if (I > 1.8632055f) {
                    const float l2 = __builtin_amdgcn_logf(1.0f - __builtin_amdgcn_rcpf(I));
                    int kc = (int)__builtin_ceilf(l2 * -13.5134035f);
                    k = kc < 1 ? 1 : (kc > 15 ? 15 : kc);
                }
                kb[(size_t)(rbase + r) * H_SZ + c] = (unsigned char)k;
            }
        }
    }
}

// ---------------------------------------------------------------- K2: bucket-sorted, static targets
// QUAD: one padded quad of entries -> 4 independent gathers; BODY consumes wa..wd.
#define QUAD(IDX, BODY)                                                       \
    { const uint2 eq = *(const uint2*)&ent[IDX];                              \
      const int sa = __builtin_amdgcn_readfirstlane((int)eq.x);               \
      const int sb = __builtin_amdgcn_readfirstlane((int)eq.y);               \
      const int ja = sa & 0xffff, jb = (sa >> 16) & 0xffff;                   \
      const int je = sb & 0xffff, jf = (sb >> 16) & 0xffff;                   \
      const uint2 wa = *(const uint2*)(W2cb + ((size_t)ja << 10) + jc);       \
      const uint2 wb = *(const uint2*)(W2cb + ((size_t)jb << 10) + jc);       \
      const uint2 wc = *(const uint2*)(W2cb + ((size_t)je << 10) + jc);       \
      const uint2 wd = *(const uint2*)(W2cb + ((size_t)jf << 10) + jc);       \
      BODY }

#define BIGLOOP(GV, K)                                                        \
    for (int i = stt[K]; i < stt[(K) + 1]; i += 4)                            \
        QUAD(i, GV += unp4(wa); GV += unp4(wb); GV += unp4(wc); GV += unp4(wd);)

#define SMLOOP(K)                                                             \
    for (int i = stt[K]; i < stt[(K) + 1]; i += 4)                            \
        QUAD(i, Ps += relu4(unp4(wa)); Ps += relu4(unp4(wb));                 \
                Ps += relu4(unp4(wc)); Ps += relu4(unp4(wd));)

#define TLOOP(K)                                                              \
    for (int i = stt[K]; i < stt[(K) + 1]; i += 4)                            \
        QUAD(i, i2 += unp4(wa); i2 += unp4(wb); i2 += unp4(wc); i2 += unp4(wd);)

#define STEP                                                                  \
    { v2 = v2 * 0.95f + i2 * 0.05f;                                           \
      if (v2.x > 1.0f) { v2.x = 0.f; ++c0; }                                  \
      if (v2.y > 1.0f) { v2.y = 0.f; ++c1; }                                  \
      if (v2.z > 1.0f) { v2.z = 0.f; ++c2; }                                  \
      if (v2.w > 1.0f) { v2.w = 0.f; ++c3; } }

__global__ __launch_bounds__(256, 4) void k2_snn(const unsigned char* __restrict__ kb,
                                                 const unsigned short* __restrict__ W2cb,
                                                 const float* __restrict__ b2,
                                                 const float* __restrict__ Wout,
                                                 const float* __restrict__ bout,
                                                 float* __restrict__ out) {
    const int b   = blockIdx.x;
    const int tid = threadIdx.x;
    const int jc  = tid * 4;

    __shared__ int cnt[16];
    __shared__ int curs[16];
    __shared__ int st[17];
    __shared__ unsigned short ent[1088];     // bucketed entries, each bucket padded to x4
    __shared__ int flag;
    __shared__ int tot;
    __shared__ float rrow[H_SZ];

    if (tid < 16) { cnt[tid] = 0; if (tid == 0) { flag = 0; tot = 0; } }
    const unsigned int kw = *(const unsigned int*)(kb + (size_t)b * H_SZ + jc);
    const f32x4 b2q = *(const f32x4*)&b2[jc];
    __syncthreads();

    if (kw) {
        #pragma unroll
        for (int u = 0; u < 4; ++u) {
            const unsigned int ku = (kw >> (8 * u)) & 0xffu;
            if (ku) atomicAdd(&cnt[ku], 1);
        }
    }
    __syncthreads();
    if (tid == 0) {
        int s = 0;
        for (int k = 1; k <= 15; ++k) {
            st[k] = s; curs[k] = s;
            s += (cnt[k] + 3) & ~3;          // pad each bucket to multiple of 4
        }
        st[16] = s;
    }
    __syncthreads();
    if (kw) {
        #pragma unroll
        for (int u = 0; u < 4; ++u) {
            const unsigned int ku = (kw >> (8 * u)) & 0xffu;
            if (ku) {
                const int p = atomicAdd(&curs[ku], 1);
                ent[p] = (unsigned short)(jc + u);
            }
        }
    }
    if (tid >= 1 && tid < 16) {              // sentinel-pad the bucket tails
        for (int p = st[tid] + cnt[tid]; p < st[tid + 1]; ++p)
            ent[p] = (unsigned short)H_SZ;   // zero row of W2cb
    }
    __syncthreads();

    int stt[17];
    #pragma unroll
    for (int k = 1; k <= 16; ++k) stt[k] = __builtin_amdgcn_readfirstlane(st[k]);

    // ---- gather: static accumulator per bucket (no dynamic targeting)
    f32x4 G8 = {0,0,0,0}, G9 = {0,0,0,0}, G10 = {0,0,0,0}, G11 = {0,0,0,0};
    f32x4 G12 = {0,0,0,0}, G13 = {0,0,0,0}, G14 = {0,0,0,0}, G15 = {0,0,0,0};
    f32x4 Ps = {0,0,0,0};
    BIGLOOP(G8, 8)   BIGLOOP(G9, 9)   BIGLOOP(G10, 10) BIGLOOP(G11, 11)
    BIGLOOP(G12, 12) BIGLOOP(G13, 13) BIGLOOP(G14, 14) BIGLOOP(G15, 15)
    SMLOOP(1) SMLOOP(2) SMLOOP(3) SMLOOP(4) SMLOOP(5) SMLOOP(6) SMLOOP(7)

    // ---- certificate: M >= max_t I2_t, exact to within Ps slack
    f32x4 gm = vmax4(G8, G9);
    gm = vmax4(gm, G10); gm = vmax4(gm, G11); gm = vmax4(gm, G12);
    gm = vmax4(gm, G13); gm = vmax4(gm, G14); gm = vmax4(gm, G15);
    const float M0 = b2q.x + Ps.x + fmaxf(gm.x, 0.f);
    const float M1 = b2q.y + Ps.y + fmaxf(gm.y, 0.f);
    const float M2 = b2q.z + Ps.z + fmaxf(gm.z, 0.f);
    const float M3 = b2q.w + Ps.w + fmaxf(gm.w, 0.f);
    if ((M0 > SKIP_THR) || (M1 > SKIP_THR) || (M2 > SKIP_THR) || (M3 > SKIP_THR))
        atomicOr(&flag, 1);
    __syncthreads();

    if (flag == 0) {                         // proven spike-free: out = bout (bit-exact)
        if (tid < D_OUT) out[(size_t)b * D_OUT + tid] = bout[tid];
        return;
    }

    // ---- rare exact path: per-step re-gather from sorted buckets (static divisors)
    f32x4 v2 = {0,0,0,0};
    int c0 = 0, c1 = 0, c2 = 0, c3 = 0;
    { f32x4 i2 = b2q; TLOOP(1) STEP }                                     // t=1
    { f32x4 i2 = b2q; TLOOP(1) TLOOP(2) STEP }                            // t=2
    { f32x4 i2 = b2q; TLOOP(1) TLOOP(3) STEP }                            // t=3
    { f32x4 i2 = b2q; TLOOP(1) TLOOP(2) TLOOP(4) STEP }                   // t=4
    { f32x4 i2 = b2q; TLOOP(1) TLOOP(5) STEP }                            // t=5
    { f32x4 i2 = b2q; TLOOP(1) TLOOP(2) TLOOP(3) TLOOP(6) STEP }          // t=6
    { f32x4 i2 = b2q; TLOOP(1) TLOOP(7) STEP }                            // t=7
    { f32x4 i2 = b2q; TLOOP(1) TLOOP(2) TLOOP(4) TLOOP(8) STEP }          // t=8
    { f32x4 i2 = b2q; TLOOP(1) TLOOP(3) TLOOP(9) STEP }                   // t=9
    { f32x4 i2 = b2q; TLOOP(1) TLOOP(2) TLOOP(5) TLOOP(10) STEP }         // t=10
    { f32x4 i2 = b2q; TLOOP(1) TLOOP(11) STEP }                           // t=11
    { f32x4 i2 = b2q; TLOOP(1) TLOOP(2) TLOOP(3) TLOOP(4) TLOOP(6) TLOOP(12) STEP } // t=12
    { f32x4 i2 = b2q; TLOOP(1) TLOOP(13) STEP }                           // t=13
    { f32x4 i2 = b2q; TLOOP(1) TLOOP(2) TLOOP(7) TLOOP(14) STEP }         // t=14
    { f32x4 i2 = b2q; TLOOP(1) TLOOP(3) TLOOP(5) TLOOP(15) STEP }         // t=15

    const int my = c0 + c1 + c2 + c3;
    if (my) atomicAdd(&tot, my);
    __syncthreads();

    if (tot == 0) {                          // simulated exactly, no s2 spikes
        if (tid < D_OUT) out[(size_t)b * D_OUT + tid] = bout[tid];
        return;
    }

    rrow[jc + 0] = (float)c0 / 15.0f;
    rrow[jc + 1] = (float)c1 / 15.0f;
    rrow[jc + 2] = (float)c2 / 15.0f;
    rrow[jc + 3] = (float)c3 / 15.0f;
    __syncthreads();
    if (tid < D_OUT) {
        float a = bout[tid];
        const float* wrow = Wout + (size_t)tid * H_SZ;
        for (int j = 0; j < H_SZ; ++j) a = fmaf(rrow[j], wrow[j], a);
        out[(size_t)b * D_OUT + tid] = a;
    }
}

// ---------------------------------------------------------------- launch
extern "C" void kernel_launch(void* const* d_in, const int* in_sizes, int n_in,
                              void* d_out, int out_size, void* d_ws, size_t ws_size,
                              hipStream_t stream) {
    const float* x    = (const float*)d_in[0];
    const float* W1   = (const float*)d_in[1];
    const float* b1   = (const float*)d_in[2];
    const float* W2   = (const float*)d_in[3];
    const float* b2   = (const float*)d_in[4];
    const float* Wout = (const float*)d_in[5];
    const float* bout = (const float*)d_in[6];
    float* out = (float*)d_out;

    char* ws = (char*)d_ws;
    unsigned short* W2cb = (unsigned short*)(ws);              // 2 MB + 2 KB pad row
    unsigned char*  kbuf = (unsigned char*)(ws + (8 << 20));   // 8 MB intervals

    k0_transpose<<<dim3(H_SZ / 32, H_SZ / 32), dim3(32, 8), 0, stream>>>(W2, W2cb);
    k1_mfma<<<dim3(B_SZ / 128, H_SZ / 128), 256, 0, stream>>>(x, W1, b1, kbuf);
    k2_snn<<<B_SZ, 256, 0, stream>>>(kbuf, W2cb, b2, Wout, bout, out);
}